// Round 6
// baseline (465.431 us; speedup 1.0000x reference)
//
#include <hip/hip_runtime.h>
#include <hip/hip_fp16.h>
#include <cstdint>

#define MB 8
#define TT 2048
#define DIMK 1024
#define CC 128
#define NG 32                 /* scan groups per batch, 4 rows each */
#define MROWS (MB*TT)         /* 16384 */
#define NPROJ 576
#define YSTR 576

using bf16x8 = __attribute__((__ext_vector_type__(8))) __bf16;
using f32x4v = __attribute__((__ext_vector_type__(4))) float;
using f32x2v = __attribute__((__ext_vector_type__(2))) float;

__device__ __forceinline__ unsigned short f2b(float f) {
    unsigned u = __float_as_uint(f);
    u += 0x7fffu + ((u >> 16) & 1u);
    return (unsigned short)(u >> 16);
}

// ---------------------------------------------------------------------------
// Casts / packing
// ---------------------------------------------------------------------------
__global__ __launch_bounds__(256) void cast_x_kernel(
    const float* __restrict__ in, unsigned short* __restrict__ outp)
{
    size_t i = ((size_t)blockIdx.x * 256 + threadIdx.x) * 8;
    float4 a = *(const float4*)(in + i);
    float4 b = *(const float4*)(in + i + 4);
    uint4 r;
    r.x = f2b(a.x) | ((unsigned)f2b(a.y) << 16);
    r.y = f2b(a.z) | ((unsigned)f2b(a.w) << 16);
    r.z = f2b(b.x) | ((unsigned)f2b(b.y) << 16);
    r.w = f2b(b.z) | ((unsigned)f2b(b.w) << 16);
    *(uint4*)(outp + i) = r;
}

// WcatT[n][k] bf16, n in [0,576): 0-127 Wq, ... 512 Wa, 513 Wb, rest 0.
__global__ __launch_bounds__(256) void pack_wt(
    const float* __restrict__ Wq, const float* __restrict__ Wk,
    const float* __restrict__ Wv, const float* __restrict__ Wg,
    const float* __restrict__ Wa, const float* __restrict__ Wb,
    unsigned short* __restrict__ WcatT)
{
    int idx = blockIdx.x * 256 + threadIdx.x;
    if (idx >= NPROJ * DIMK) return;
    int n = idx >> 10, k = idx & 1023;
    float v = 0.f;
    if      (n < 128) v = Wq[k * 128 + n];
    else if (n < 256) v = Wk[k * 128 + (n - 128)];
    else if (n < 384) v = Wv[k * 128 + (n - 256)];
    else if (n < 512) v = Wg[k * 128 + (n - 384)];
    else if (n == 512) v = Wa[k];
    else if (n == 513) v = Wb[k];
    WcatT[idx] = f2b(v);
}

__global__ void pack_bias(const float* __restrict__ bq, const float* __restrict__ bk,
                          const float* __restrict__ bv, const float* __restrict__ bg,
                          const float* __restrict__ ba, const float* __restrict__ bb,
                          float* __restrict__ biascat)
{
    int n = threadIdx.x;
    if (n >= NPROJ) return;
    float v = 0.f;
    if      (n < 128) v = bq[n];
    else if (n < 256) v = bk[n - 128];
    else if (n < 384) v = bv[n - 256];
    else if (n < 512) v = bg[n - 384];
    else if (n == 512) v = ba[0];
    else if (n == 513) v = bb[0];
    biascat[n] = v;
}

// WoT[n][k] bf16 (Wo is [CC][DIM])
__global__ __launch_bounds__(256) void cast_wot(
    const float* __restrict__ Wo, unsigned short* __restrict__ WoT)
{
    int idx = blockIdx.x * 256 + threadIdx.x;
    if (idx >= DIMK * CC) return;
    int n = idx >> 7, k = idx & 127;
    WoT[idx] = f2b(Wo[k * DIMK + n]);
}

// ---------------------------------------------------------------------------
// BF16 MFMA GEMM: C[M][N] = A[MxK bf16] @ BT[NxK bf16]^T + bias, fp32 out.
// ---------------------------------------------------------------------------
__global__ __launch_bounds__(256) void gemm_bt_bf16(
    const unsigned short* __restrict__ A, const unsigned short* __restrict__ BT,
    const float* __restrict__ bias, float* __restrict__ C,
    int M, int N, int K)
{
    __shared__ unsigned short As[4][128][8];   // [k-quad][m][j]
    __shared__ unsigned short Bs[4][64][8];    // [k-quad][n][j]
    int tid = threadIdx.x;
    int w = tid >> 6, l = tid & 63;
    int lm = l & 15, lq = l >> 4;
    int bm = blockIdx.y * 128, bn = blockIdx.x * 64;

    f32x4v acc[2][4];
#pragma unroll
    for (int rt = 0; rt < 2; rt++)
#pragma unroll
        for (int ct = 0; ct < 4; ct++) acc[rt][ct] = (f32x4v)(0.f);

    int ar = tid >> 1, ah = tid & 1;          // A stage: row ar, 16-elem half ah
    int brn = tid >> 2, bq = tid & 3;         // B stage: row brn, 8-elem quarter
    const unsigned short* Arow = A + (size_t)(bm + ar) * K + ah * 16;
    const unsigned short* Brow = BT + (size_t)(bn + brn) * K + bq * 8;

    for (int kk = 0; kk < K; kk += 32) {
        uint4 av0 = *(const uint4*)(Arow + kk);
        uint4 av1 = *(const uint4*)(Arow + kk + 8);
        uint4 bv  = *(const uint4*)(Brow + kk);
        __syncthreads();
        *(uint4*)&As[ah * 2][ar][0]     = av0;
        *(uint4*)&As[ah * 2 + 1][ar][0] = av1;
        *(uint4*)&Bs[bq][brn][0]        = bv;
        __syncthreads();
        bf16x8 af[2], bf[4];
#pragma unroll
        for (int rt = 0; rt < 2; rt++)
            __builtin_memcpy(&af[rt], &As[lq][w * 32 + rt * 16 + lm][0], 16);
#pragma unroll
        for (int ct = 0; ct < 4; ct++)
            __builtin_memcpy(&bf[ct], &Bs[lq][ct * 16 + lm][0], 16);
#pragma unroll
        for (int rt = 0; rt < 2; rt++)
#pragma unroll
            for (int ct = 0; ct < 4; ct++)
                acc[rt][ct] = __builtin_amdgcn_mfma_f32_16x16x32_bf16(
                    af[rt], bf[ct], acc[rt][ct], 0, 0, 0);
    }
#pragma unroll
    for (int rt = 0; rt < 2; rt++)
#pragma unroll
        for (int ct = 0; ct < 4; ct++) {
            int col = bn + ct * 16 + lm;
            float bcol = bias[col];
#pragma unroll
            for (int i = 0; i < 4; i++) {
                int row = bm + w * 32 + rt * 16 + lq * 4 + i;
                C[(size_t)row * N + col] = acc[rt][ct][i] + bcol;
            }
        }
}

// ---------------------------------------------------------------------------
// Post-projection (unchanged)
// ---------------------------------------------------------------------------
__global__ __launch_bounds__(64) void postproj_kernel(
    const float* __restrict__ Y, float* __restrict__ knorm,
    float* __restrict__ gbuf, float4* __restrict__ qvab)
{
    int m = blockIdx.x;
    int lane = threadIdx.x;
    int b = m >> 11, t = m & (TT - 1);
    const float* yr = Y + (size_t)m * YSTR;
    float k0 = yr[128 + lane], k1 = yr[192 + lane];
    float ss = k0 * k0 + k1 * k1;
#pragma unroll
    for (int mask = 1; mask < 64; mask <<= 1) ss += __shfl_xor(ss, mask);
    float inv = 1.0f / fmaxf(sqrtf(ss), 1e-12f);
    knorm[(size_t)m * CC + lane]      = k0 * inv;
    knorm[(size_t)m * CC + 64 + lane] = k1 * inv;
    float g0 = yr[384 + lane], g1 = yr[448 + lane];
    gbuf[(size_t)m * CC + lane]      = 1.f / (1.f + expf(-g0));
    gbuf[(size_t)m * CC + 64 + lane] = 1.f / (1.f + expf(-g1));
    float a  = 1.f / (1.f + expf(-yr[512]));
    float bb = 1.f / (1.f + expf(-yr[513]));
    {
        int i = lane;
        qvab[((size_t)(b * NG + (i >> 2)) * TT + t) * 4 + (i & 3)] =
            make_float4(yr[i], yr[256 + i], a, bb);
        i = lane + 64;
        qvab[((size_t)(b * NG + (i >> 2)) * TT + t) * 4 + (i & 3)] =
            make_float4(yr[i], yr[256 + i], a, bb);
    }
}

// ---------------------------------------------------------------------------
// Cross-lane helpers
// ---------------------------------------------------------------------------
__device__ __forceinline__ float dpp_add_xor1(float p) {
    int i = __builtin_amdgcn_mov_dpp(__float_as_int(p), 0xB1, 0xF, 0xF, true);
    return p + __int_as_float(i);
}
__device__ __forceinline__ float dpp_add_xor2(float p) {
    int i = __builtin_amdgcn_mov_dpp(__float_as_int(p), 0x4E, 0xF, 0xF, true);
    return p + __int_as_float(i);
}
__device__ __forceinline__ float dpp_add_mirror7(float p) {
    int i = __builtin_amdgcn_mov_dpp(__float_as_int(p), 0x141, 0xF, 0xF, true);
    return p + __int_as_float(i);
}
__device__ __forceinline__ float dpp_add_ror8(float p) {
    int i = __builtin_amdgcn_mov_dpp(__float_as_int(p), 0x128, 0xF, 0xF, true);
    return p + __int_as_float(i);
}
__device__ __forceinline__ int h2i(__half2 h) { int i; __builtin_memcpy(&i, &h, 4); return i; }
__device__ __forceinline__ __half2 i2h(int i) { __half2 h; __builtin_memcpy(&h, &i, 4); return h; }

// packed f32 helpers (lower to v_pk_mul_f32 / v_pk_fma_f32 on CDNA)
__device__ __forceinline__ f32x2v vfma2(f32x2v a, f32x2v b, f32x2v c) {
#if __has_builtin(__builtin_elementwise_fma)
    return __builtin_elementwise_fma(a, b, c);
#else
    return a * b + c;
#endif
}
__device__ __forceinline__ __half2 cvt2h(f32x2v v) {
    return __float22half2_rn(make_float2(v.x, v.y));
}

// gfx950 VALU-pipe cross-row swaps (no LDS pipe, no lgkmcnt).
__device__ __forceinline__ void pl16_swap(unsigned &a, unsigned &b) {
#if __has_builtin(__builtin_amdgcn_permlane16_swap)
    auto r = __builtin_amdgcn_permlane16_swap(a, b, false, false);
    a = (unsigned)r[0]; b = (unsigned)r[1];
#else
    asm volatile("v_permlane16_swap_b32 %0, %1" : "+v"(a), "+v"(b));
#endif
}
__device__ __forceinline__ void pl32_swap(unsigned &a, unsigned &b) {
#if __has_builtin(__builtin_amdgcn_permlane32_swap)
    auto r = __builtin_amdgcn_permlane32_swap(a, b, false, false);
    a = (unsigned)r[0]; b = (unsigned)r[1];
#else
    asm volatile("v_permlane32_swap_b32 %0, %1" : "+v"(a), "+v"(b));
#endif
}
// reduce helpers: p + p[lane^16], p + p[lane^32] (copy + swap + add)
__device__ __forceinline__ float pl16_add(float p) {
    unsigned a = __float_as_uint(p), b = a;
    pl16_swap(a, b);
    return __uint_as_float(a) + __uint_as_float(b);
}
__device__ __forceinline__ float pl32_add(float p) {
    unsigned a = __float_as_uint(p), b = a;
    pl32_swap(a, b);
    return __uint_as_float(a) + __uint_as_float(b);
}
// full 64-lane sum, bit-identical tree to R5
__device__ __forceinline__ float red6(float h) {
    h = dpp_add_xor1(h);
    h = dpp_add_xor2(h);
    h = dpp_add_mirror7(h);
    h = dpp_add_ror8(h);
    h = pl16_add(h);
    h = pl32_add(h);
    return h;
}

// async global->LDS, 16B/lane, 1024B/instruction.
__device__ __forceinline__ void gload_lds16(const void* g, void* l) {
    __builtin_amdgcn_global_load_lds(
        (const __attribute__((address_space(1))) void*)g,
        (__attribute__((address_space(3))) void*)l, 16, 0, 0);
}

// ---------------------------------------------------------------------------
// Sequential scan, 4 waves/block (one state-row per wave). Grid = MB*NG =
// 256 blocks x 256 threads.
//
// R6 change (R5 post-mortem: 236 cy/step with ~140 cy serial chain; the
// 6-stage cross-lane reduce sat INSIDE the step's dependency chain with
// nothing to interleave): LOOKAHEAD REDUCE. p_{t+1} = <s_{t+1}, k_{t+1}>,
// and s_{t+1} is ready right after cr_t — so the reduce for NEXT step's p
// is launched at the end of step t (k_{t+1} already prefetched) and
// consumed at the top of step t+1. One full step of slack; the compiler
// interleaves the 14-instr reduce chain with LDK/unpack/output/combine.
// Bit-identical arithmetic to R5 (same muls, same reduce tree, reordered).
//  * chunk boundary: step CH-1's lookahead needs next chunk's k[0] (not
//    yet waited) -> deferred to the top of the next chunk, where it
//    overlaps the distributed combine.
//  * COMBINE distributed into the step loop (one slice per 4 steps) as
//    gap-filler for the reduce chain. vmcnt schedule unchanged from R5
//    (per-wave FIFO: [stage(c) 4-6][8 stores][stage(c+1) 4-6] -> 12).
// ---------------------------------------------------------------------------
#define CH  32                 /* steps per chunk */
#define NCH (TT/CH)            /* 64 chunks */

template <bool ATOMIC>
__global__ __launch_bounds__(256, 1) void scan_kernel(
    const float* __restrict__ knorm, const float4* __restrict__ qvab,
    void* __restrict__ outp)
{
    __shared__ float lk[2 * CH * 128];        // 2 x 16 KiB k chunks
    __shared__ float lq[2 * CH * 16];         // 2 x 2 KiB qvab chunks
    __shared__ unsigned outb[2 * 4 * CH * 64]; // 2 x 32 KiB partial buffers

    int blk = blockIdx.x;
    int b = blk >> 5;
    int gi = blk & 31;
    int tid = threadIdx.x;
    int w = tid >> 6, lane = tid & 63;
    f32x2v s2v = (f32x2v)(0.f);
    float pred = 0.f;            // reduce result for the CURRENT step's p
    size_t mbase = (size_t)b * TT;

    const char* kgb = (const char*)(knorm + mbase * CC);
    const char* qgb = (const char*)(qvab + (size_t)blk * TT * 4);
    size_t lane16 = (size_t)lane * 16;

#define STAGE_CHUNK(cc, bf) do {                                              \
    char* lkd = (char*)lk + (size_t)(bf) * (CH * 512) + (size_t)w * 4096;     \
    const char* kc_ = kgb + (size_t)(cc) * (CH * 512) + (size_t)w * 4096;     \
    _Pragma("unroll")                                                         \
    for (int i_ = 0; i_ < 4; ++i_)                                            \
        gload_lds16(kc_ + (size_t)i_ * 1024 + lane16, lkd + i_ * 1024);       \
    if (w == 0) {                                                             \
        char* lqd = (char*)lq + (size_t)(bf) * (CH * 64);                     \
        const char* qc_ = qgb + (size_t)(cc) * (CH * 64);                     \
        gload_lds16(qc_ + lane16, lqd);                                       \
        gload_lds16(qc_ + 1024 + lane16, lqd + 1024);                         \
    }                                                                         \
} while (0)

#define LDK(st, sl) do {                                                      \
    kP[sl] = *(const f32x2v*)(lkc + (st) * 128 + lane * 2);                   \
    qP[sl] = *(const f32x4v*)(lqc + (st) * 16 + w * 4);                       \
} while (0)

// one slice (32 of 256 outputs) of the 4-row combine for chunk cc
#define COMBINE_ONE(cc, j_) do {                                              \
    const unsigned* ob_ = outb + (size_t)((cc) & 1) * (4 * CH * 64);          \
    int slot_ = tid + 256 * (j_);                                             \
    int st_ = slot_ >> 6, ln_ = slot_ & 63;                                   \
    __half2 h0_ = i2h((int)ob_[(0 * CH + st_) * 64 + ln_]);                   \
    __half2 h1_ = i2h((int)ob_[(1 * CH + st_) * 64 + ln_]);                   \
    __half2 h2_ = i2h((int)ob_[(2 * CH + st_) * 64 + ln_]);                   \
    __half2 h3_ = i2h((int)ob_[(3 * CH + st_) * 64 + ln_]);                   \
    __half2 r_ = __hadd2(__hadd2(h0_, h1_), __hadd2(h2_, h3_));               \
    size_t m_ = mbase + (size_t)(cc) * CH + st_;                              \
    if (ATOMIC) {                                                             \
        float2 f_ = __half22float2(r_);                                       \
        float* op_ = (float*)outp + m_ * CC + ln_ * 2;                        \
        atomicAdd(op_, f_.x);                                                 \
        atomicAdd(op_ + 1, f_.y);                                             \
    } else {                                                                  \
        ((unsigned*)outp)[((size_t)gi * MROWS + m_) * 64 + ln_] =             \
            (unsigned)h2i(r_);                                                \
    }                                                                         \
} while (0)

    STAGE_CHUNK(0, 0);

    for (int c = 0; c < NCH; ++c) {
        int cur = c & 1;
        if (c + 1 < NCH) STAGE_CHUNK(c + 1, cur ^ 1);
        // wait for chunk c's staging (per-wave FIFO vmcnt; never drain to 0)
        if (c < 2) {
            asm volatile("s_waitcnt vmcnt(4)" ::: "memory");
        } else if (c + 1 < NCH) {
            asm volatile("s_waitcnt vmcnt(12)" ::: "memory");
        } else {
            asm volatile("s_waitcnt vmcnt(8)" ::: "memory");
        }
        asm volatile("s_waitcnt lgkmcnt(0)" ::: "memory");
        __builtin_amdgcn_s_barrier();

        const float* lkc = lk + (size_t)cur * CH * 128;
        const float* lqc = lq + (size_t)cur * CH * 16;
        unsigned* obw = outb + (size_t)(cur * 4 + w) * CH * 64 + lane;

        if (c > 0) {
            // deferred boundary lookahead: p for step c*CH uses this chunk's
            // k row 0 (now staged); overlaps with the distributed combine.
            f32x2v kb = *(const f32x2v*)(lkc + lane * 2);
            f32x2v nb = s2v * kb;
            pred = red6(nb[0] + nb[1]);
        }

        f32x2v kP[4];
        f32x4v qP[4];
        LDK(0, 0); LDK(1, 1); LDK(2, 2);
#pragma unroll
        for (int st = 0; st < CH; ++st) {
            if (st + 3 < CH) LDK(st + 3, (st + 3) & 3);
            f32x2v k2 = kP[st & 3];
            f32x4v qv = qP[st & 3];
            float q_ = qv[0], v_ = qv[1], at_ = qv[2], bt_ = qv[3];
            float ba_ = at_ * bt_, bv_ = bt_ * v_;
            float cr_ = fmaf(-ba_, pred, bv_);
            f32x2v at2_ = {at_, at_};
            f32x2v cr2_ = {cr_, cr_};
            f32x2v q2_  = {q_, q_};
            s2v = vfma2(k2, cr2_, s2v * at2_);
            __half2 pb_ = cvt2h(q2_ * s2v);
            obw[st * 64] = (unsigned)h2i(pb_);
            if (st < CH - 1) {
                // lookahead reduce for next step's p = <s_{t+1}, k_{t+1}>
                f32x2v kn = kP[(st + 1) & 3];
                f32x2v ns = s2v * kn;
                pred = red6(ns[0] + ns[1]);
            }
            if ((st & 3) == 3 && c > 0) COMBINE_ONE(c - 1, st >> 2);
        }
    }
    asm volatile("s_waitcnt lgkmcnt(0)" ::: "memory");
    __builtin_amdgcn_s_barrier();
#pragma unroll
    for (int j = 0; j < 8; ++j) COMBINE_ONE(NCH - 1, j);
#undef STAGE_CHUNK
#undef LDK
#undef COMBINE_ONE
}

// ---------------------------------------------------------------------------
// Combine f16x2 partials over NG groups, apply gate, emit bf16 pair.
// ---------------------------------------------------------------------------
__global__ __launch_bounds__(256) void combine_kernel(
    const unsigned* __restrict__ opart,
    const float* __restrict__ gbuf, unsigned* __restrict__ ocombb)
{
    size_t idx = (size_t)blockIdx.x * 256 + threadIdx.x;  // < MROWS*64
    float sx = 0.f, sy = 0.f;
#pragma unroll
    for (int gi = 0; gi < NG; ++gi) {
        __half2 h = i2h((int)opart[(size_t)gi * MROWS * 64 + idx]);
        float2 f = __half22float2(h);
        sx += f.x; sy += f.y;
    }
    float2 g = *(const float2*)(gbuf + idx * 2);
    ocombb[idx] = f2b(sx * g.x) | ((unsigned)f2b(sy * g.y) << 16);
}

__global__ __launch_bounds__(256) void gate_kernel(
    const float* __restrict__ ocombf, const float* __restrict__ gbuf,
    unsigned short* __restrict__ ocombb)
{
    size_t idx = (size_t)blockIdx.x * 256 + threadIdx.x;  // < MROWS*CC
    ocombb[idx] = f2b(ocombf[idx] * gbuf[idx]);
}

// ---------------------------------------------------------------------------
extern "C" void kernel_launch(void* const* d_in, const int* in_sizes, int n_in,
                              void* d_out, int out_size, void* d_ws, size_t ws_size,
                              hipStream_t stream)
{
    const float* x  = (const float*)d_in[0];
    const float* Wq = (const float*)d_in[1];
    const float* bq = (const float*)d_in[2];
    const float* Wk = (const float*)d_in[3];
    const float* bk = (const float*)d_in[4];
    const float* Wv = (const float*)d_in[5];
    const float* bv = (const float*)d_in[6];
    const float* Wa = (const float*)d_in[7];
    const float* ba = (const float*)d_in[8];
    const float* Wb = (const float*)d_in[9];
    const float* bb = (const float*)d_in[10];
    const float* Wg = (const float*)d_in[11];
    const float* bg = (const float*)d_in[12];
    const float* Wo = (const float*)d_in[13];
    const float* bo = (const float*)d_in[14];
    float* out = (float*)d_out;

    // ---- workspace layout (floats), with aliasing:
    //  qvab aliases xb (xb dead after proj GEMM; qvab written by postproj)
    //  opart aliases Y and beyond (Y dead after postproj)
    //  ocombf (atomic fallback) aliases opart
    float* ws = (float*)d_ws;
    size_t off = 0;
    float* knorm   = ws + off; off += (size_t)MROWS * CC;        // 2.10M
    float* gbuf    = ws + off; off += (size_t)MROWS * CC;        // 2.10M
    unsigned* ocombb = (unsigned*)(ws + off); off += (size_t)MROWS * CC / 2;
    unsigned short* WcatT = (unsigned short*)(ws + off); off += (size_t)NPROJ * DIMK / 2;
    unsigned short* WoT   = (unsigned short*)(ws + off); off += (size_t)DIMK * CC / 2;
    float* biascat = ws + off; off += NPROJ;
    unsigned short* xb = (unsigned short*)(ws + off);
    float* qvab    = ws + off; off += (size_t)MROWS * DIMK / 2;  // 8.39M (both)
    float* Y       = ws + off;
    size_t opart_off = off;
    off += (size_t)MROWS * YSTR;                                  // Y end
    float* ocombf  = ws + opart_off;
    unsigned* opart = (unsigned*)(ws + opart_off);
    size_t opart_end = opart_off + (size_t)NG * MROWS * 64;
    size_t need_big = (opart_end > off ? opart_end : off) * sizeof(float);
    bool big = ws_size >= need_big;

    hipLaunchKernelGGL(cast_x_kernel, dim3((size_t)MROWS * DIMK / 8 / 256), dim3(256), 0, stream,
                       x, xb);
    hipLaunchKernelGGL(pack_wt, dim3(NPROJ * DIMK / 256), dim3(256), 0, stream,
                       Wq, Wk, Wv, Wg, Wa, Wb, WcatT);
    hipLaunchKernelGGL(pack_bias, dim3(1), dim3(NPROJ), 0, stream,
                       bq, bk, bv, bg, ba, bb, biascat);
    hipLaunchKernelGGL(cast_wot, dim3(DIMK * CC / 256), dim3(256), 0, stream,
                       Wo, WoT);
    // projection GEMM: Y[16384][576] = xb @ WcatT^T + biascat
    hipLaunchKernelGGL(gemm_bt_bf16, dim3(NPROJ / 64, MROWS / 128), dim3(256), 0, stream,
                       xb, WcatT, biascat, Y, MROWS, NPROJ, DIMK);
    hipLaunchKernelGGL(postproj_kernel, dim3(MROWS), dim3(64), 0, stream,
                       Y, knorm, gbuf, (float4*)qvab);
    if (big) {
        hipLaunchKernelGGL((scan_kernel<false>), dim3(MB * NG), dim3(256), 0, stream,
                           knorm, (const float4*)qvab, (void*)opart);
        hipLaunchKernelGGL(combine_kernel, dim3(MROWS * 64 / 256), dim3(256), 0, stream,
                           opart, gbuf, ocombb);
    } else {
        (void)hipMemsetAsync(ocombf, 0, (size_t)MROWS * CC * sizeof(float), stream);
        hipLaunchKernelGGL((scan_kernel<true>), dim3(MB * NG), dim3(256), 0, stream,
                           knorm, (const float4*)qvab, (void*)ocombf);
        hipLaunchKernelGGL(gate_kernel, dim3(MROWS * CC / 256), dim3(256), 0, stream,
                           ocombf, gbuf, (unsigned short*)ocombb);
    }
    // output GEMM: out[16384][1024] = ocombb @ WoT^T + bo
    hipLaunchKernelGGL(gemm_bt_bf16, dim3(DIMK / 64, MROWS / 128), dim3(256), 0, stream,
                       (const unsigned short*)ocombb, WoT, bo, out, MROWS, DIMK, CC);
}

// Round 8
// 465.244 us; speedup vs baseline: 1.0004x; 1.0004x over previous
//
#include <hip/hip_runtime.h>
#include <hip/hip_fp16.h>
#include <cstdint>

#define MB 8
#define TT 2048
#define DIMK 1024
#define CC 128
#define NG 32                 /* scan groups per batch, 4 rows each */
#define MROWS (MB*TT)         /* 16384 */
#define NPROJ 576
#define YSTR 576

using bf16x8 = __attribute__((__ext_vector_type__(8))) __bf16;
using f32x4v = __attribute__((__ext_vector_type__(4))) float;
using f32x2v = __attribute__((__ext_vector_type__(2))) float;

__device__ __forceinline__ unsigned short f2b(float f) {
    unsigned u = __float_as_uint(f);
    u += 0x7fffu + ((u >> 16) & 1u);
    return (unsigned short)(u >> 16);
}

// async global->LDS, 16B/lane, 1024B/instruction. LDS dest is wave-uniform
// base + lane*16 (HW); global src is per-lane.
__device__ __forceinline__ void gload_lds16(const void* g, void* l) {
    __builtin_amdgcn_global_load_lds(
        (const __attribute__((address_space(1))) void*)g,
        (__attribute__((address_space(3))) void*)l, 16, 0, 0);
}

// ---------------------------------------------------------------------------
// Casts / packing
// ---------------------------------------------------------------------------
__global__ __launch_bounds__(256) void cast_x_kernel(
    const float* __restrict__ in, unsigned short* __restrict__ outp)
{
    size_t i = ((size_t)blockIdx.x * 256 + threadIdx.x) * 8;
    float4 a = *(const float4*)(in + i);
    float4 b = *(const float4*)(in + i + 4);
    uint4 r;
    r.x = f2b(a.x) | ((unsigned)f2b(a.y) << 16);
    r.y = f2b(a.z) | ((unsigned)f2b(a.w) << 16);
    r.z = f2b(b.x) | ((unsigned)f2b(b.y) << 16);
    r.w = f2b(b.z) | ((unsigned)f2b(b.w) << 16);
    *(uint4*)(outp + i) = r;
}

// WcatT[n][k] bf16, n in [0,576): 0-127 Wq, ... 512 Wa, 513 Wb, rest 0.
__global__ __launch_bounds__(256) void pack_wt(
    const float* __restrict__ Wq, const float* __restrict__ Wk,
    const float* __restrict__ Wv, const float* __restrict__ Wg,
    const float* __restrict__ Wa, const float* __restrict__ Wb,
    unsigned short* __restrict__ WcatT)
{
    int idx = blockIdx.x * 256 + threadIdx.x;
    if (idx >= NPROJ * DIMK) return;
    int n = idx >> 10, k = idx & 1023;
    float v = 0.f;
    if      (n < 128) v = Wq[k * 128 + n];
    else if (n < 256) v = Wk[k * 128 + (n - 128)];
    else if (n < 384) v = Wv[k * 128 + (n - 256)];
    else if (n < 512) v = Wg[k * 128 + (n - 384)];
    else if (n == 512) v = Wa[k];
    else if (n == 513) v = Wb[k];
    WcatT[idx] = f2b(v);
}

__global__ void pack_bias(const float* __restrict__ bq, const float* __restrict__ bk,
                          const float* __restrict__ bv, const float* __restrict__ bg,
                          const float* __restrict__ ba, const float* __restrict__ bb,
                          float* __restrict__ biascat)
{
    int n = threadIdx.x;
    if (n >= NPROJ) return;
    float v = 0.f;
    if      (n < 128) v = bq[n];
    else if (n < 256) v = bk[n - 128];
    else if (n < 384) v = bv[n - 256];
    else if (n < 512) v = bg[n - 384];
    else if (n == 512) v = ba[0];
    else if (n == 513) v = bb[0];
    biascat[n] = v;
}

// WoT[n][k] bf16 (Wo is [CC][DIM])
__global__ __launch_bounds__(256) void cast_wot(
    const float* __restrict__ Wo, unsigned short* __restrict__ WoT)
{
    int idx = blockIdx.x * 256 + threadIdx.x;
    if (idx >= DIMK * CC) return;
    int n = idx >> 7, k = idx & 127;
    WoT[idx] = f2b(Wo[k * DIMK + n]);
}

// ---------------------------------------------------------------------------
// BF16 MFMA GEMM: C[M][N] = A[MxK bf16] @ BT[NxK bf16]^T + bias, fp32 out.
// Tile 128(M) x 64(N), BK=32, 4 waves.
//
// Staging via async global_load_lds (width 16), double-buffered LDS,
// counted s_waitcnt vmcnt(3) + raw s_barrier. LDS layout [kq][m][8] and the
// whole read/MFMA/epilogue side are UNCHANGED -> bit-identical results; the
// layout stays 2-way-bank (free) on ds_read_b128.
// Stage ownership: wave w stages A kq=w (rows 0-63 and 64-127, 2 instrs)
// and B kq=w (rows 0-63, 1 instr): As[kq][m][j] holds A[bm+m][kk+kq*8+j].
// ---------------------------------------------------------------------------
__global__ __launch_bounds__(256) void gemm_bt_bf16(
    const unsigned short* __restrict__ A, const unsigned short* __restrict__ BT,
    const float* __restrict__ bias, float* __restrict__ C,
    int M, int N, int K)
{
    __shared__ unsigned short As[2][4][128][8];   // [buf][k-quad][m][j]
    __shared__ unsigned short Bs[2][4][64][8];    // [buf][k-quad][n][j]
    int tid = threadIdx.x;
    int w = tid >> 6, l = tid & 63;
    int lm = l & 15, lq = l >> 4;
    int bm = blockIdx.y * 128, bn = blockIdx.x * 64;

    f32x4v acc[2][4];
#pragma unroll
    for (int rt = 0; rt < 2; rt++)
#pragma unroll
        for (int ct = 0; ct < 4; ct++) acc[rt][ct] = (f32x4v)(0.f);

    // per-lane global sources for this wave's staging slice (kq = w)
    const char* Asrc0 = (const char*)(A + (size_t)(bm + l) * K) + w * 16;
    const char* Asrc1 = (const char*)(A + (size_t)(bm + 64 + l) * K) + w * 16;
    const char* Bsrc  = (const char*)(BT + (size_t)(bn + l) * K) + w * 16;

#define GSTAGE(kk, bf) do {                                                   \
    gload_lds16(Asrc0 + (size_t)(kk) * 2, &As[bf][w][0][0]);                  \
    gload_lds16(Asrc1 + (size_t)(kk) * 2, &As[bf][w][64][0]);                 \
    gload_lds16(Bsrc  + (size_t)(kk) * 2, &Bs[bf][w][0][0]);                  \
} while (0)

    GSTAGE(0, 0);
    int nk = K >> 5;
    for (int ik = 0; ik < nk; ++ik) {
        int bufc = ik & 1;
        if (ik + 1 < nk) {
            GSTAGE((ik + 1) << 5, bufc ^ 1);
            asm volatile("s_waitcnt vmcnt(3)" ::: "memory");  // current tile landed
        } else {
            asm volatile("s_waitcnt vmcnt(0)" ::: "memory");
        }
        __builtin_amdgcn_s_barrier();
        bf16x8 af[2], bf[4];
#pragma unroll
        for (int rt = 0; rt < 2; rt++)
            __builtin_memcpy(&af[rt], &As[bufc][lq][w * 32 + rt * 16 + lm][0], 16);
#pragma unroll
        for (int ct = 0; ct < 4; ct++)
            __builtin_memcpy(&bf[ct], &Bs[bufc][lq][ct * 16 + lm][0], 16);
#pragma unroll
        for (int rt = 0; rt < 2; rt++)
#pragma unroll
            for (int ct = 0; ct < 4; ct++)
                acc[rt][ct] = __builtin_amdgcn_mfma_f32_16x16x32_bf16(
                    af[rt], bf[ct], acc[rt][ct], 0, 0, 0);
        __builtin_amdgcn_s_barrier();   // protect buf from next iter's stage
    }
#undef GSTAGE
#pragma unroll
    for (int rt = 0; rt < 2; rt++)
#pragma unroll
        for (int ct = 0; ct < 4; ct++) {
            int col = bn + ct * 16 + lm;
            float bcol = bias[col];
#pragma unroll
            for (int i = 0; i < 4; i++) {
                int row = bm + w * 32 + rt * 16 + lq * 4 + i;
                C[(size_t)row * N + col] = acc[rt][ct][i] + bcol;
            }
        }
}

// ---------------------------------------------------------------------------
// Post-projection (unchanged)
// ---------------------------------------------------------------------------
__global__ __launch_bounds__(64) void postproj_kernel(
    const float* __restrict__ Y, float* __restrict__ knorm,
    float* __restrict__ gbuf, float4* __restrict__ qvab)
{
    int m = blockIdx.x;
    int lane = threadIdx.x;
    int b = m >> 11, t = m & (TT - 1);
    const float* yr = Y + (size_t)m * YSTR;
    float k0 = yr[128 + lane], k1 = yr[192 + lane];
    float ss = k0 * k0 + k1 * k1;
#pragma unroll
    for (int mask = 1; mask < 64; mask <<= 1) ss += __shfl_xor(ss, mask);
    float inv = 1.0f / fmaxf(sqrtf(ss), 1e-12f);
    knorm[(size_t)m * CC + lane]      = k0 * inv;
    knorm[(size_t)m * CC + 64 + lane] = k1 * inv;
    float g0 = yr[384 + lane], g1 = yr[448 + lane];
    gbuf[(size_t)m * CC + lane]      = 1.f / (1.f + expf(-g0));
    gbuf[(size_t)m * CC + 64 + lane] = 1.f / (1.f + expf(-g1));
    float a  = 1.f / (1.f + expf(-yr[512]));
    float bb = 1.f / (1.f + expf(-yr[513]));
    {
        int i = lane;
        qvab[((size_t)(b * NG + (i >> 2)) * TT + t) * 4 + (i & 3)] =
            make_float4(yr[i], yr[256 + i], a, bb);
        i = lane + 64;
        qvab[((size_t)(b * NG + (i >> 2)) * TT + t) * 4 + (i & 3)] =
            make_float4(yr[i], yr[256 + i], a, bb);
    }
}

// ---------------------------------------------------------------------------
// Cross-lane helpers
// ---------------------------------------------------------------------------
__device__ __forceinline__ float dpp_add_xor1(float p) {
    int i = __builtin_amdgcn_mov_dpp(__float_as_int(p), 0xB1, 0xF, 0xF, true);
    return p + __int_as_float(i);
}
__device__ __forceinline__ float dpp_add_xor2(float p) {
    int i = __builtin_amdgcn_mov_dpp(__float_as_int(p), 0x4E, 0xF, 0xF, true);
    return p + __int_as_float(i);
}
__device__ __forceinline__ float dpp_add_mirror7(float p) {
    int i = __builtin_amdgcn_mov_dpp(__float_as_int(p), 0x141, 0xF, 0xF, true);
    return p + __int_as_float(i);
}
__device__ __forceinline__ float dpp_add_ror8(float p) {
    int i = __builtin_amdgcn_mov_dpp(__float_as_int(p), 0x128, 0xF, 0xF, true);
    return p + __int_as_float(i);
}
__device__ __forceinline__ int h2i(__half2 h) { int i; __builtin_memcpy(&i, &h, 4); return i; }
__device__ __forceinline__ __half2 i2h(int i) { __half2 h; __builtin_memcpy(&h, &i, 4); return h; }

// packed f32 helpers (lower to v_pk_mul_f32 / v_pk_fma_f32 on CDNA)
__device__ __forceinline__ f32x2v vfma2(f32x2v a, f32x2v b, f32x2v c) {
#if __has_builtin(__builtin_elementwise_fma)
    return __builtin_elementwise_fma(a, b, c);
#else
    return a * b + c;
#endif
}
__device__ __forceinline__ __half2 cvt2h(f32x2v v) {
    return __float22half2_rn(make_float2(v.x, v.y));
}

// gfx950 VALU-pipe cross-row swaps (no LDS pipe, no lgkmcnt).
__device__ __forceinline__ void pl16_swap(unsigned &a, unsigned &b) {
#if __has_builtin(__builtin_amdgcn_permlane16_swap)
    auto r = __builtin_amdgcn_permlane16_swap(a, b, false, false);
    a = (unsigned)r[0]; b = (unsigned)r[1];
#else
    asm volatile("v_permlane16_swap_b32 %0, %1" : "+v"(a), "+v"(b));
#endif
}
__device__ __forceinline__ void pl32_swap(unsigned &a, unsigned &b) {
#if __has_builtin(__builtin_amdgcn_permlane32_swap)
    auto r = __builtin_amdgcn_permlane32_swap(a, b, false, false);
    a = (unsigned)r[0]; b = (unsigned)r[1];
#else
    asm volatile("v_permlane32_swap_b32 %0, %1" : "+v"(a), "+v"(b));
#endif
}
// reduce helpers: p + p[lane^16], p + p[lane^32] (copy + swap + add)
__device__ __forceinline__ float pl16_add(float p) {
    unsigned a = __float_as_uint(p), b = a;
    pl16_swap(a, b);
    return __uint_as_float(a) + __uint_as_float(b);
}
__device__ __forceinline__ float pl32_add(float p) {
    unsigned a = __float_as_uint(p), b = a;
    pl32_swap(a, b);
    return __uint_as_float(a) + __uint_as_float(b);
}

// ---------------------------------------------------------------------------
// Sequential scan, 4 waves/block (one state-row per wave). Grid = MB*NG =
// 256 blocks x 256 threads. EXACT R5 structure (R6's lookahead-reduce
// regressed: it did not shorten the s->p->c->s critical path, only added
// bookkeeping; reverted).
// ---------------------------------------------------------------------------
#define CH  32                 /* steps per chunk */
#define NCH (TT/CH)            /* 64 chunks */

template <bool ATOMIC>
__global__ __launch_bounds__(256, 1) void scan_kernel(
    const float* __restrict__ knorm, const float4* __restrict__ qvab,
    void* __restrict__ outp)
{
    __shared__ float lk[2 * CH * 128];        // 2 x 16 KiB k chunks
    __shared__ float lq[2 * CH * 16];         // 2 x 2 KiB qvab chunks
    __shared__ unsigned outb[2 * 4 * CH * 64]; // 2 x 32 KiB partial buffers

    int blk = blockIdx.x;
    int b = blk >> 5;
    int gi = blk & 31;
    int tid = threadIdx.x;
    int w = tid >> 6, lane = tid & 63;
    f32x2v s2v = (f32x2v)(0.f);
    size_t mbase = (size_t)b * TT;

    const char* kgb = (const char*)(knorm + mbase * CC);
    const char* qgb = (const char*)(qvab + (size_t)blk * TT * 4);
    size_t lane16 = (size_t)lane * 16;

#define STAGE_CHUNK(cc, bf) do {                                              \
    char* lkd = (char*)lk + (size_t)(bf) * (CH * 512) + (size_t)w * 4096;     \
    const char* kc_ = kgb + (size_t)(cc) * (CH * 512) + (size_t)w * 4096;     \
    _Pragma("unroll")                                                         \
    for (int i_ = 0; i_ < 4; ++i_)                                            \
        gload_lds16(kc_ + (size_t)i_ * 1024 + lane16, lkd + i_ * 1024);       \
    if (w == 0) {                                                             \
        char* lqd = (char*)lq + (size_t)(bf) * (CH * 64);                     \
        const char* qc_ = qgb + (size_t)(cc) * (CH * 64);                     \
        gload_lds16(qc_ + lane16, lqd);                                       \
        gload_lds16(qc_ + 1024 + lane16, lqd + 1024);                         \
    }                                                                         \
} while (0)

#define LDK(st, sl) do {                                                      \
    kP[sl] = *(const f32x2v*)(lkc + (st) * 128 + lane * 2);                   \
    qP[sl] = *(const f32x4v*)(lqc + (st) * 16 + w * 4);                       \
} while (0)

#define KSTEP(st, sl) do {                                                    \
    f32x2v k2 = kP[sl];                                                       \
    f32x4v qv = qP[sl];                                                       \
    float q_ = qv[0], v_ = qv[1], at_ = qv[2], bt_ = qv[3];                   \
    f32x2v ps_ = s2v * k2;                                                    \
    float p_ = ps_[0] + ps_[1];                                               \
    p_ = dpp_add_xor1(p_);                                                    \
    p_ = dpp_add_xor2(p_);                                                    \
    p_ = dpp_add_mirror7(p_);                                                 \
    p_ = dpp_add_ror8(p_);                                                    \
    p_ = pl16_add(p_);                                                        \
    p_ = pl32_add(p_);                                                        \
    float ba_ = at_ * bt_, bv_ = bt_ * v_;                                    \
    float cr_ = fmaf(-ba_, p_, bv_);                                          \
    f32x2v at2_ = {at_, at_};                                                 \
    f32x2v cr2_ = {cr_, cr_};                                                 \
    f32x2v q2_  = {q_, q_};                                                   \
    s2v = vfma2(k2, cr2_, s2v * at2_);                                        \
    __half2 pb_ = cvt2h(q2_ * s2v);                                           \
    obw[(st) * 64] = (unsigned)h2i(pb_);                                      \
} while (0)

#define COMBINE(cc) do {                                                      \
    const unsigned* ob_ = outb + (size_t)((cc) & 1) * (4 * CH * 64);          \
    int tg_ = (cc) * CH;                                                      \
    _Pragma("unroll")                                                         \
    for (int j_ = 0; j_ < 8; ++j_) {                                          \
        int slot_ = tid + 256 * j_;                                           \
        int st_ = slot_ >> 6, ln_ = slot_ & 63;                               \
        __half2 h0_ = i2h((int)ob_[(0 * CH + st_) * 64 + ln_]);               \
        __half2 h1_ = i2h((int)ob_[(1 * CH + st_) * 64 + ln_]);               \
        __half2 h2_ = i2h((int)ob_[(2 * CH + st_) * 64 + ln_]);               \
        __half2 h3_ = i2h((int)ob_[(3 * CH + st_) * 64 + ln_]);               \
        __half2 r_ = __hadd2(__hadd2(h0_, h1_), __hadd2(h2_, h3_));           \
        size_t m_ = mbase + tg_ + st_;                                        \
        if (ATOMIC) {                                                         \
            float2 f_ = __half22float2(r_);                                   \
            float* op_ = (float*)outp + m_ * CC + ln_ * 2;                    \
            atomicAdd(op_, f_.x);                                             \
            atomicAdd(op_ + 1, f_.y);                                         \
        } else {                                                              \
            ((unsigned*)outp)[((size_t)gi * MROWS + m_) * 64 + ln_] =         \
                (unsigned)h2i(r_);                                            \
        }                                                                     \
    }                                                                         \
} while (0)

    STAGE_CHUNK(0, 0);

    for (int c = 0; c < NCH; ++c) {
        int cur = c & 1;
        if (c + 1 < NCH) STAGE_CHUNK(c + 1, cur ^ 1);
        // wait for chunk c's staging (per-wave FIFO vmcnt; never drain to 0)
        if (c < 2) {
            asm volatile("s_waitcnt vmcnt(4)" ::: "memory");
        } else if (c + 1 < NCH) {
            asm volatile("s_waitcnt vmcnt(12)" ::: "memory");
        } else {
            asm volatile("s_waitcnt vmcnt(8)" ::: "memory");
        }
        asm volatile("s_waitcnt lgkmcnt(0)" ::: "memory");
        __builtin_amdgcn_s_barrier();
        if (c > 0) COMBINE(c - 1);

        const float* lkc = lk + (size_t)cur * CH * 128;
        const float* lqc = lq + (size_t)cur * CH * 16;
        unsigned* obw = outb + (size_t)(cur * 4 + w) * CH * 64 + lane;

        f32x2v kP[4];
        f32x4v qP[4];
        LDK(0, 0); LDK(1, 1); LDK(2, 2);
#pragma unroll
        for (int st = 0; st < CH; ++st) {
            if (st + 3 < CH) LDK(st + 3, (st + 3) & 3);
            KSTEP(st, st & 3);
        }
    }
    asm volatile("s_waitcnt lgkmcnt(0)" ::: "memory");
    __builtin_amdgcn_s_barrier();
    COMBINE(NCH - 1);
#undef STAGE_CHUNK
#undef LDK
#undef KSTEP
#undef COMBINE
}

// ---------------------------------------------------------------------------
// Combine f16x2 partials over NG groups, apply gate, emit bf16 pair.
// ---------------------------------------------------------------------------
__global__ __launch_bounds__(256) void combine_kernel(
    const unsigned* __restrict__ opart,
    const float* __restrict__ gbuf, unsigned* __restrict__ ocombb)
{
    size_t idx = (size_t)blockIdx.x * 256 + threadIdx.x;  // < MROWS*64
    float sx = 0.f, sy = 0.f;
#pragma unroll
    for (int gi = 0; gi < NG; ++gi) {
        __half2 h = i2h((int)opart[(size_t)gi * MROWS * 64 + idx]);
        float2 f = __half22float2(h);
        sx += f.x; sy += f.y;
    }
    float2 g = *(const float2*)(gbuf + idx * 2);
    ocombb[idx] = f2b(sx * g.x) | ((unsigned)f2b(sy * g.y) << 16);
}

__global__ __launch_bounds__(256) void gate_kernel(
    const float* __restrict__ ocombf, const float* __restrict__ gbuf,
    unsigned short* __restrict__ ocombb)
{
    size_t idx = (size_t)blockIdx.x * 256 + threadIdx.x;  // < MROWS*CC
    ocombb[idx] = f2b(ocombf[idx] * gbuf[idx]);
}

// ---------------------------------------------------------------------------
extern "C" void kernel_launch(void* const* d_in, const int* in_sizes, int n_in,
                              void* d_out, int out_size, void* d_ws, size_t ws_size,
                              hipStream_t stream)
{
    const float* x  = (const float*)d_in[0];
    const float* Wq = (const float*)d_in[1];
    const float* bq = (const float*)d_in[2];
    const float* Wk = (const float*)d_in[3];
    const float* bk = (const float*)d_in[4];
    const float* Wv = (const float*)d_in[5];
    const float* bv = (const float*)d_in[6];
    const float* Wa = (const float*)d_in[7];
    const float* ba = (const float*)d_in[8];
    const float* Wb = (const float*)d_in[9];
    const float* bb = (const float*)d_in[10];
    const float* Wg = (const float*)d_in[11];
    const float* bg = (const float*)d_in[12];
    const float* Wo = (const float*)d_in[13];
    const float* bo = (const float*)d_in[14];
    float* out = (float*)d_out;

    // ---- workspace layout (floats), with aliasing:
    //  qvab aliases xb (xb dead after proj GEMM; qvab written by postproj)
    //  opart aliases Y and beyond (Y dead after postproj)
    //  ocombf (atomic fallback) aliases opart
    float* ws = (float*)d_ws;
    size_t off = 0;
    float* knorm   = ws + off; off += (size_t)MROWS * CC;        // 2.10M
    float* gbuf    = ws + off; off += (size_t)MROWS * CC;        // 2.10M
    unsigned* ocombb = (unsigned*)(ws + off); off += (size_t)MROWS * CC / 2;
    unsigned short* WcatT = (unsigned short*)(ws + off); off += (size_t)NPROJ * DIMK / 2;
    unsigned short* WoT   = (unsigned short*)(ws + off); off += (size_t)DIMK * CC / 2;
    float* biascat = ws + off; off += NPROJ;
    unsigned short* xb = (unsigned short*)(ws + off);
    float* qvab    = ws + off; off += (size_t)MROWS * DIMK / 2;  // 8.39M (both)
    float* Y       = ws + off;
    size_t opart_off = off;
    off += (size_t)MROWS * YSTR;                                  // Y end
    float* ocombf  = ws + opart_off;
    unsigned* opart = (unsigned*)(ws + opart_off);
    size_t opart_end = opart_off + (size_t)NG * MROWS * 64;
    size_t need_big = (opart_end > off ? opart_end : off) * sizeof(float);
    bool big = ws_size >= need_big;

    hipLaunchKernelGGL(cast_x_kernel, dim3((size_t)MROWS * DIMK / 8 / 256), dim3(256), 0, stream,
                       x, xb);
    hipLaunchKernelGGL(pack_wt, dim3(NPROJ * DIMK / 256), dim3(256), 0, stream,
                       Wq, Wk, Wv, Wg, Wa, Wb, WcatT);
    hipLaunchKernelGGL(pack_bias, dim3(1), dim3(NPROJ), 0, stream,
                       bq, bk, bv, bg, ba, bb, biascat);
    hipLaunchKernelGGL(cast_wot, dim3(DIMK * CC / 256), dim3(256), 0, stream,
                       Wo, WoT);
    // projection GEMM: Y[16384][576] = xb @ WcatT^T + biascat
    hipLaunchKernelGGL(gemm_bt_bf16, dim3(NPROJ / 64, MROWS / 128), dim3(256), 0, stream,
                       xb, WcatT, biascat, Y, MROWS, NPROJ, DIMK);
    hipLaunchKernelGGL(postproj_kernel, dim3(MROWS), dim3(64), 0, stream,
                       Y, knorm, gbuf, (float4*)qvab);
    if (big) {
        hipLaunchKernelGGL((scan_kernel<false>), dim3(MB * NG), dim3(256), 0, stream,
                           knorm, (const float4*)qvab, (void*)opart);
        hipLaunchKernelGGL(combine_kernel, dim3(MROWS * 64 / 256), dim3(256), 0, stream,
                           opart, gbuf, ocombb);
    } else {
        (void)hipMemsetAsync(ocombf, 0, (size_t)MROWS * CC * sizeof(float), stream);
        hipLaunchKernelGGL((scan_kernel<true>), dim3(MB * NG), dim3(256), 0, stream,
                           knorm, (const float4*)qvab, (void*)ocombf);
        hipLaunchKernelGGL(gate_kernel, dim3(MROWS * CC / 256), dim3(256), 0, stream,
                           ocombf, gbuf, (unsigned short*)ocombb);
    }
    // output GEMM: out[16384][1024] = ocombb @ WoT^T + bo
    hipLaunchKernelGGL(gemm_bt_bf16, dim3(DIMK / 64, MROWS / 128), dim3(256), 0, stream,
                       (const unsigned short*)ocombb, WoT, bo, out, MROWS, DIMK, CC);
}

// Round 9
// 457.195 us; speedup vs baseline: 1.0180x; 1.0176x over previous
//
#include <hip/hip_runtime.h>
#include <hip/hip_fp16.h>
#include <cstdint>

#define MB 8
#define TT 2048
#define DIMK 1024
#define CC 128
#define NG 32                 /* scan groups per batch, 4 rows each */
#define MROWS (MB*TT)         /* 16384 */
#define NPROJ 576
#define YSTR 576

using bf16x8 = __attribute__((__ext_vector_type__(8))) __bf16;
using f32x4v = __attribute__((__ext_vector_type__(4))) float;
using f32x2v = __attribute__((__ext_vector_type__(2))) float;

__device__ __forceinline__ unsigned short f2b(float f) {
    unsigned u = __float_as_uint(f);
    u += 0x7fffu + ((u >> 16) & 1u);
    return (unsigned short)(u >> 16);
}

// async global->LDS, 16B/lane, 1024B/instruction (used by the scan).
__device__ __forceinline__ void gload_lds16(const void* g, void* l) {
    __builtin_amdgcn_global_load_lds(
        (const __attribute__((address_space(1))) void*)g,
        (__attribute__((address_space(3))) void*)l, 16, 0, 0);
}

// ---------------------------------------------------------------------------
// Packing
// ---------------------------------------------------------------------------
// WcatT[n][k] bf16, n in [0,576): 0-127 Wq, ... 512 Wa, 513 Wb, rest 0.
__global__ __launch_bounds__(256) void pack_wt(
    const float* __restrict__ Wq, const float* __restrict__ Wk,
    const float* __restrict__ Wv, const float* __restrict__ Wg,
    const float* __restrict__ Wa, const float* __restrict__ Wb,
    unsigned short* __restrict__ WcatT)
{
    int idx = blockIdx.x * 256 + threadIdx.x;
    if (idx >= NPROJ * DIMK) return;
    int n = idx >> 10, k = idx & 1023;
    float v = 0.f;
    if      (n < 128) v = Wq[k * 128 + n];
    else if (n < 256) v = Wk[k * 128 + (n - 128)];
    else if (n < 384) v = Wv[k * 128 + (n - 256)];
    else if (n < 512) v = Wg[k * 128 + (n - 384)];
    else if (n == 512) v = Wa[k];
    else if (n == 513) v = Wb[k];
    WcatT[idx] = f2b(v);
}

__global__ void pack_bias(const float* __restrict__ bq, const float* __restrict__ bk,
                          const float* __restrict__ bv, const float* __restrict__ bg,
                          const float* __restrict__ ba, const float* __restrict__ bb,
                          float* __restrict__ biascat)
{
    int n = threadIdx.x;
    if (n >= NPROJ) return;
    float v = 0.f;
    if      (n < 128) v = bq[n];
    else if (n < 256) v = bk[n - 128];
    else if (n < 384) v = bv[n - 256];
    else if (n < 512) v = bg[n - 384];
    else if (n == 512) v = ba[0];
    else if (n == 513) v = bb[0];
    biascat[n] = v;
}

// WoT[n][k] bf16 (Wo is [CC][DIM])
__global__ __launch_bounds__(256) void cast_wot(
    const float* __restrict__ Wo, unsigned short* __restrict__ WoT)
{
    int idx = blockIdx.x * 256 + threadIdx.x;
    if (idx >= DIMK * CC) return;
    int n = idx >> 7, k = idx & 127;
    WoT[idx] = f2b(Wo[k * DIMK + n]);
}

// ---------------------------------------------------------------------------
// BF16 MFMA GEMM: C[M][N] = A[MxK] @ BT[NxK bf16]^T + bias, fp32 out.
// Tile 128(M) x 64(N), BK=32, 4 waves. R5/R6 register-staged structure
// (R8's global_load_lds variant regressed ~27us: 16B/row gathers + vmcnt(3)
// covering only one MFMA phase of HBM latency; reverted).
//
// Template AF32: A is f32 (proj GEMM reads x directly, converts with the
// SAME f2b as the old cast_x kernel in-register before the ds_write ->
// bit-identical MFMA inputs, cast_x kernel + xb round-trip deleted).
// AF32=false: A is bf16 (out GEMM) — byte-identical to the R5 kernel.
// ---------------------------------------------------------------------------
template <bool AF32>
__global__ __launch_bounds__(256) void gemm_bt_bf16(
    const void* __restrict__ Avp, const unsigned short* __restrict__ BT,
    const float* __restrict__ bias, float* __restrict__ C,
    int M, int N, int K)
{
    __shared__ unsigned short As[4][128][8];   // [k-quad][m][j]
    __shared__ unsigned short Bs[4][64][8];    // [k-quad][n][j]
    int tid = threadIdx.x;
    int w = tid >> 6, l = tid & 63;
    int lm = l & 15, lq = l >> 4;
    int bm = blockIdx.y * 128, bn = blockIdx.x * 64;

    f32x4v acc[2][4];
#pragma unroll
    for (int rt = 0; rt < 2; rt++)
#pragma unroll
        for (int ct = 0; ct < 4; ct++) acc[rt][ct] = (f32x4v)(0.f);

    int ar = tid >> 1, ah = tid & 1;          // A stage: row ar, 16-elem half ah
    int brn = tid >> 2, bq = tid & 3;         // B stage: row brn, 8-elem quarter
    const unsigned short* Arow16 =
        (const unsigned short*)Avp + (size_t)(bm + ar) * K + ah * 16;
    const float* Arow32 =
        (const float*)Avp + (size_t)(bm + ar) * K + ah * 16;
    const unsigned short* Brow = BT + (size_t)(bn + brn) * K + bq * 8;

    for (int kk = 0; kk < K; kk += 32) {
        uint4 av0, av1;
        if (AF32) {
            float4 f0 = *(const float4*)(Arow32 + kk);
            float4 f1 = *(const float4*)(Arow32 + kk + 4);
            float4 f2 = *(const float4*)(Arow32 + kk + 8);
            float4 f3 = *(const float4*)(Arow32 + kk + 12);
            av0.x = f2b(f0.x) | ((unsigned)f2b(f0.y) << 16);
            av0.y = f2b(f0.z) | ((unsigned)f2b(f0.w) << 16);
            av0.z = f2b(f1.x) | ((unsigned)f2b(f1.y) << 16);
            av0.w = f2b(f1.z) | ((unsigned)f2b(f1.w) << 16);
            av1.x = f2b(f2.x) | ((unsigned)f2b(f2.y) << 16);
            av1.y = f2b(f2.z) | ((unsigned)f2b(f2.w) << 16);
            av1.z = f2b(f3.x) | ((unsigned)f2b(f3.y) << 16);
            av1.w = f2b(f3.z) | ((unsigned)f2b(f3.w) << 16);
        } else {
            av0 = *(const uint4*)(Arow16 + kk);
            av1 = *(const uint4*)(Arow16 + kk + 8);
        }
        uint4 bv  = *(const uint4*)(Brow + kk);
        __syncthreads();
        *(uint4*)&As[ah * 2][ar][0]     = av0;
        *(uint4*)&As[ah * 2 + 1][ar][0] = av1;
        *(uint4*)&Bs[bq][brn][0]        = bv;
        __syncthreads();
        bf16x8 af[2], bf[4];
#pragma unroll
        for (int rt = 0; rt < 2; rt++)
            __builtin_memcpy(&af[rt], &As[lq][w * 32 + rt * 16 + lm][0], 16);
#pragma unroll
        for (int ct = 0; ct < 4; ct++)
            __builtin_memcpy(&bf[ct], &Bs[lq][ct * 16 + lm][0], 16);
#pragma unroll
        for (int rt = 0; rt < 2; rt++)
#pragma unroll
            for (int ct = 0; ct < 4; ct++)
                acc[rt][ct] = __builtin_amdgcn_mfma_f32_16x16x32_bf16(
                    af[rt], bf[ct], acc[rt][ct], 0, 0, 0);
    }
#pragma unroll
    for (int rt = 0; rt < 2; rt++)
#pragma unroll
        for (int ct = 0; ct < 4; ct++) {
            int col = bn + ct * 16 + lm;
            float bcol = bias[col];
#pragma unroll
            for (int i = 0; i < 4; i++) {
                int row = bm + w * 32 + rt * 16 + lq * 4 + i;
                C[(size_t)row * N + col] = acc[rt][ct][i] + bcol;
            }
        }
}

// ---------------------------------------------------------------------------
// Post-projection (unchanged)
// ---------------------------------------------------------------------------
__global__ __launch_bounds__(64) void postproj_kernel(
    const float* __restrict__ Y, float* __restrict__ knorm,
    float* __restrict__ gbuf, float4* __restrict__ qvab)
{
    int m = blockIdx.x;
    int lane = threadIdx.x;
    int b = m >> 11, t = m & (TT - 1);
    const float* yr = Y + (size_t)m * YSTR;
    float k0 = yr[128 + lane], k1 = yr[192 + lane];
    float ss = k0 * k0 + k1 * k1;
#pragma unroll
    for (int mask = 1; mask < 64; mask <<= 1) ss += __shfl_xor(ss, mask);
    float inv = 1.0f / fmaxf(sqrtf(ss), 1e-12f);
    knorm[(size_t)m * CC + lane]      = k0 * inv;
    knorm[(size_t)m * CC + 64 + lane] = k1 * inv;
    float g0 = yr[384 + lane], g1 = yr[448 + lane];
    gbuf[(size_t)m * CC + lane]      = 1.f / (1.f + expf(-g0));
    gbuf[(size_t)m * CC + 64 + lane] = 1.f / (1.f + expf(-g1));
    float a  = 1.f / (1.f + expf(-yr[512]));
    float bb = 1.f / (1.f + expf(-yr[513]));
    {
        int i = lane;
        qvab[((size_t)(b * NG + (i >> 2)) * TT + t) * 4 + (i & 3)] =
            make_float4(yr[i], yr[256 + i], a, bb);
        i = lane + 64;
        qvab[((size_t)(b * NG + (i >> 2)) * TT + t) * 4 + (i & 3)] =
            make_float4(yr[i], yr[256 + i], a, bb);
    }
}

// ---------------------------------------------------------------------------
// Cross-lane helpers
// ---------------------------------------------------------------------------
__device__ __forceinline__ float dpp_add_xor1(float p) {
    int i = __builtin_amdgcn_mov_dpp(__float_as_int(p), 0xB1, 0xF, 0xF, true);
    return p + __int_as_float(i);
}
__device__ __forceinline__ float dpp_add_xor2(float p) {
    int i = __builtin_amdgcn_mov_dpp(__float_as_int(p), 0x4E, 0xF, 0xF, true);
    return p + __int_as_float(i);
}
__device__ __forceinline__ float dpp_add_mirror7(float p) {
    int i = __builtin_amdgcn_mov_dpp(__float_as_int(p), 0x141, 0xF, 0xF, true);
    return p + __int_as_float(i);
}
__device__ __forceinline__ float dpp_add_ror8(float p) {
    int i = __builtin_amdgcn_mov_dpp(__float_as_int(p), 0x128, 0xF, 0xF, true);
    return p + __int_as_float(i);
}
__device__ __forceinline__ int h2i(__half2 h) { int i; __builtin_memcpy(&i, &h, 4); return i; }
__device__ __forceinline__ __half2 i2h(int i) { __half2 h; __builtin_memcpy(&h, &i, 4); return h; }

// packed f32 helpers (lower to v_pk_mul_f32 / v_pk_fma_f32 on CDNA)
__device__ __forceinline__ f32x2v vfma2(f32x2v a, f32x2v b, f32x2v c) {
#if __has_builtin(__builtin_elementwise_fma)
    return __builtin_elementwise_fma(a, b, c);
#else
    return a * b + c;
#endif
}
__device__ __forceinline__ __half2 cvt2h(f32x2v v) {
    return __float22half2_rn(make_float2(v.x, v.y));
}

// gfx950 VALU-pipe cross-row swaps (no LDS pipe, no lgkmcnt).
__device__ __forceinline__ void pl16_swap(unsigned &a, unsigned &b) {
#if __has_builtin(__builtin_amdgcn_permlane16_swap)
    auto r = __builtin_amdgcn_permlane16_swap(a, b, false, false);
    a = (unsigned)r[0]; b = (unsigned)r[1];
#else
    asm volatile("v_permlane16_swap_b32 %0, %1" : "+v"(a), "+v"(b));
#endif
}
__device__ __forceinline__ void pl32_swap(unsigned &a, unsigned &b) {
#if __has_builtin(__builtin_amdgcn_permlane32_swap)
    auto r = __builtin_amdgcn_permlane32_swap(a, b, false, false);
    a = (unsigned)r[0]; b = (unsigned)r[1];
#else
    asm volatile("v_permlane32_swap_b32 %0, %1" : "+v"(a), "+v"(b));
#endif
}
// reduce helpers: p + p[lane^16], p + p[lane^32] (copy + swap + add)
__device__ __forceinline__ float pl16_add(float p) {
    unsigned a = __float_as_uint(p), b = a;
    pl16_swap(a, b);
    return __uint_as_float(a) + __uint_as_float(b);
}
__device__ __forceinline__ float pl32_add(float p) {
    unsigned a = __float_as_uint(p), b = a;
    pl32_swap(a, b);
    return __uint_as_float(a) + __uint_as_float(b);
}

// ---------------------------------------------------------------------------
// Sequential scan, 4 waves/block (one state-row per wave). Grid = MB*NG =
// 256 blocks x 256 threads. EXACT R5 structure (verified 200 us twice).
// ---------------------------------------------------------------------------
#define CH  32                 /* steps per chunk */
#define NCH (TT/CH)            /* 64 chunks */

template <bool ATOMIC>
__global__ __launch_bounds__(256, 1) void scan_kernel(
    const float* __restrict__ knorm, const float4* __restrict__ qvab,
    void* __restrict__ outp)
{
    __shared__ float lk[2 * CH * 128];        // 2 x 16 KiB k chunks
    __shared__ float lq[2 * CH * 16];         // 2 x 2 KiB qvab chunks
    __shared__ unsigned outb[2 * 4 * CH * 64]; // 2 x 32 KiB partial buffers

    int blk = blockIdx.x;
    int b = blk >> 5;
    int gi = blk & 31;
    int tid = threadIdx.x;
    int w = tid >> 6, lane = tid & 63;
    f32x2v s2v = (f32x2v)(0.f);
    size_t mbase = (size_t)b * TT;

    const char* kgb = (const char*)(knorm + mbase * CC);
    const char* qgb = (const char*)(qvab + (size_t)blk * TT * 4);
    size_t lane16 = (size_t)lane * 16;

#define STAGE_CHUNK(cc, bf) do {                                              \
    char* lkd = (char*)lk + (size_t)(bf) * (CH * 512) + (size_t)w * 4096;     \
    const char* kc_ = kgb + (size_t)(cc) * (CH * 512) + (size_t)w * 4096;     \
    _Pragma("unroll")                                                         \
    for (int i_ = 0; i_ < 4; ++i_)                                            \
        gload_lds16(kc_ + (size_t)i_ * 1024 + lane16, lkd + i_ * 1024);       \
    if (w == 0) {                                                             \
        char* lqd = (char*)lq + (size_t)(bf) * (CH * 64);                     \
        const char* qc_ = qgb + (size_t)(cc) * (CH * 64);                     \
        gload_lds16(qc_ + lane16, lqd);                                       \
        gload_lds16(qc_ + 1024 + lane16, lqd + 1024);                         \
    }                                                                         \
} while (0)

#define LDK(st, sl) do {                                                      \
    kP[sl] = *(const f32x2v*)(lkc + (st) * 128 + lane * 2);                   \
    qP[sl] = *(const f32x4v*)(lqc + (st) * 16 + w * 4);                       \
} while (0)

#define KSTEP(st, sl) do {                                                    \
    f32x2v k2 = kP[sl];                                                       \
    f32x4v qv = qP[sl];                                                       \
    float q_ = qv[0], v_ = qv[1], at_ = qv[2], bt_ = qv[3];                   \
    f32x2v ps_ = s2v * k2;                                                    \
    float p_ = ps_[0] + ps_[1];                                               \
    p_ = dpp_add_xor1(p_);                                                    \
    p_ = dpp_add_xor2(p_);                                                    \
    p_ = dpp_add_mirror7(p_);                                                 \
    p_ = dpp_add_ror8(p_);                                                    \
    p_ = pl16_add(p_);                                                        \
    p_ = pl32_add(p_);                                                        \
    float ba_ = at_ * bt_, bv_ = bt_ * v_;                                    \
    float cr_ = fmaf(-ba_, p_, bv_);                                          \
    f32x2v at2_ = {at_, at_};                                                 \
    f32x2v cr2_ = {cr_, cr_};                                                 \
    f32x2v q2_  = {q_, q_};                                                   \
    s2v = vfma2(k2, cr2_, s2v * at2_);                                        \
    __half2 pb_ = cvt2h(q2_ * s2v);                                           \
    obw[(st) * 64] = (unsigned)h2i(pb_);                                      \
} while (0)

#define COMBINE(cc) do {                                                      \
    const unsigned* ob_ = outb + (size_t)((cc) & 1) * (4 * CH * 64);          \
    int tg_ = (cc) * CH;                                                      \
    _Pragma("unroll")                                                         \
    for (int j_ = 0; j_ < 8; ++j_) {                                          \
        int slot_ = tid + 256 * j_;                                           \
        int st_ = slot_ >> 6, ln_ = slot_ & 63;                               \
        __half2 h0_ = i2h((int)ob_[(0 * CH + st_) * 64 + ln_]);               \
        __half2 h1_ = i2h((int)ob_[(1 * CH + st_) * 64 + ln_]);               \
        __half2 h2_ = i2h((int)ob_[(2 * CH + st_) * 64 + ln_]);               \
        __half2 h3_ = i2h((int)ob_[(3 * CH + st_) * 64 + ln_]);               \
        __half2 r_ = __hadd2(__hadd2(h0_, h1_), __hadd2(h2_, h3_));           \
        size_t m_ = mbase + tg_ + st_;                                        \
        if (ATOMIC) {                                                         \
            float2 f_ = __half22float2(r_);                                   \
            float* op_ = (float*)outp + m_ * CC + ln_ * 2;                    \
            atomicAdd(op_, f_.x);                                             \
            atomicAdd(op_ + 1, f_.y);                                         \
        } else {                                                              \
            ((unsigned*)outp)[((size_t)gi * MROWS + m_) * 64 + ln_] =         \
                (unsigned)h2i(r_);                                            \
        }                                                                     \
    }                                                                         \
} while (0)

    STAGE_CHUNK(0, 0);

    for (int c = 0; c < NCH; ++c) {
        int cur = c & 1;
        if (c + 1 < NCH) STAGE_CHUNK(c + 1, cur ^ 1);
        // wait for chunk c's staging (per-wave FIFO vmcnt; never drain to 0)
        if (c < 2) {
            asm volatile("s_waitcnt vmcnt(4)" ::: "memory");
        } else if (c + 1 < NCH) {
            asm volatile("s_waitcnt vmcnt(12)" ::: "memory");
        } else {
            asm volatile("s_waitcnt vmcnt(8)" ::: "memory");
        }
        asm volatile("s_waitcnt lgkmcnt(0)" ::: "memory");
        __builtin_amdgcn_s_barrier();
        if (c > 0) COMBINE(c - 1);

        const float* lkc = lk + (size_t)cur * CH * 128;
        const float* lqc = lq + (size_t)cur * CH * 16;
        unsigned* obw = outb + (size_t)(cur * 4 + w) * CH * 64 + lane;

        f32x2v kP[4];
        f32x4v qP[4];
        LDK(0, 0); LDK(1, 1); LDK(2, 2);
#pragma unroll
        for (int st = 0; st < CH; ++st) {
            if (st + 3 < CH) LDK(st + 3, (st + 3) & 3);
            KSTEP(st, st & 3);
        }
    }
    asm volatile("s_waitcnt lgkmcnt(0)" ::: "memory");
    __builtin_amdgcn_s_barrier();
    COMBINE(NCH - 1);
#undef STAGE_CHUNK
#undef LDK
#undef KSTEP
#undef COMBINE
}

// ---------------------------------------------------------------------------
// Combine f16x2 partials over NG groups, apply gate, emit bf16 pair.
// ---------------------------------------------------------------------------
__global__ __launch_bounds__(256) void combine_kernel(
    const unsigned* __restrict__ opart,
    const float* __restrict__ gbuf, unsigned* __restrict__ ocombb)
{
    size_t idx = (size_t)blockIdx.x * 256 + threadIdx.x;  // < MROWS*64
    float sx = 0.f, sy = 0.f;
#pragma unroll
    for (int gi = 0; gi < NG; ++gi) {
        __half2 h = i2h((int)opart[(size_t)gi * MROWS * 64 + idx]);
        float2 f = __half22float2(h);
        sx += f.x; sy += f.y;
    }
    float2 g = *(const float2*)(gbuf + idx * 2);
    ocombb[idx] = f2b(sx * g.x) | ((unsigned)f2b(sy * g.y) << 16);
}

__global__ __launch_bounds__(256) void gate_kernel(
    const float* __restrict__ ocombf, const float* __restrict__ gbuf,
    unsigned short* __restrict__ ocombb)
{
    size_t idx = (size_t)blockIdx.x * 256 + threadIdx.x;  // < MROWS*CC
    ocombb[idx] = f2b(ocombf[idx] * gbuf[idx]);
}

// ---------------------------------------------------------------------------
extern "C" void kernel_launch(void* const* d_in, const int* in_sizes, int n_in,
                              void* d_out, int out_size, void* d_ws, size_t ws_size,
                              hipStream_t stream)
{
    const float* x  = (const float*)d_in[0];
    const float* Wq = (const float*)d_in[1];
    const float* bq = (const float*)d_in[2];
    const float* Wk = (const float*)d_in[3];
    const float* bk = (const float*)d_in[4];
    const float* Wv = (const float*)d_in[5];
    const float* bv = (const float*)d_in[6];
    const float* Wa = (const float*)d_in[7];
    const float* ba = (const float*)d_in[8];
    const float* Wb = (const float*)d_in[9];
    const float* bb = (const float*)d_in[10];
    const float* Wg = (const float*)d_in[11];
    const float* bg = (const float*)d_in[12];
    const float* Wo = (const float*)d_in[13];
    const float* bo = (const float*)d_in[14];
    float* out = (float*)d_out;

    // ---- workspace layout (floats), with aliasing:
    //  qvab occupies the old xb slot (xb is gone: proj GEMM reads x directly)
    //  opart aliases Y and beyond (Y dead after postproj)
    //  ocombf (atomic fallback) aliases opart
    float* ws = (float*)d_ws;
    size_t off = 0;
    float* knorm   = ws + off; off += (size_t)MROWS * CC;        // 2.10M
    float* gbuf    = ws + off; off += (size_t)MROWS * CC;        // 2.10M
    unsigned* ocombb = (unsigned*)(ws + off); off += (size_t)MROWS * CC / 2;
    unsigned short* WcatT = (unsigned short*)(ws + off); off += (size_t)NPROJ * DIMK / 2;
    unsigned short* WoT   = (unsigned short*)(ws + off); off += (size_t)DIMK * CC / 2;
    float* biascat = ws + off; off += NPROJ;
    float* qvab    = ws + off; off += (size_t)MROWS * DIMK / 2;  // 8.39M
    float* Y       = ws + off;
    size_t opart_off = off;
    off += (size_t)MROWS * YSTR;                                  // Y end
    float* ocombf  = ws + opart_off;
    unsigned* opart = (unsigned*)(ws + opart_off);
    size_t opart_end = opart_off + (size_t)NG * MROWS * 64;
    size_t need_big = (opart_end > off ? opart_end : off) * sizeof(float);
    bool big = ws_size >= need_big;

    hipLaunchKernelGGL(pack_wt, dim3(NPROJ * DIMK / 256), dim3(256), 0, stream,
                       Wq, Wk, Wv, Wg, Wa, Wb, WcatT);
    hipLaunchKernelGGL(pack_bias, dim3(1), dim3(NPROJ), 0, stream,
                       bq, bk, bv, bg, ba, bb, biascat);
    hipLaunchKernelGGL(cast_wot, dim3(DIMK * CC / 256), dim3(256), 0, stream,
                       Wo, WoT);
    // projection GEMM: Y[16384][576] = bf16(x) @ WcatT^T + biascat
    // (f32 A path converts in-register with the same f2b -> bit-identical)
    hipLaunchKernelGGL((gemm_bt_bf16<true>), dim3(NPROJ / 64, MROWS / 128), dim3(256), 0, stream,
                       (const void*)x, WcatT, biascat, Y, MROWS, NPROJ, DIMK);
    hipLaunchKernelGGL(postproj_kernel, dim3(MROWS), dim3(64), 0, stream,
                       Y, knorm, gbuf, (float4*)qvab);
    if (big) {
        hipLaunchKernelGGL((scan_kernel<false>), dim3(MB * NG), dim3(256), 0, stream,
                           knorm, (const float4*)qvab, (void*)opart);
        hipLaunchKernelGGL(combine_kernel, dim3(MROWS * 64 / 256), dim3(256), 0, stream,
                           opart, gbuf, ocombb);
    } else {
        (void)hipMemsetAsync(ocombf, 0, (size_t)MROWS * CC * sizeof(float), stream);
        hipLaunchKernelGGL((scan_kernel<true>), dim3(MB * NG), dim3(256), 0, stream,
                           knorm, (const float4*)qvab, (void*)ocombf);
        hipLaunchKernelGGL(gate_kernel, dim3(MROWS * CC / 256), dim3(256), 0, stream,
                           ocombf, gbuf, (unsigned short*)ocombb);
    }
    // output GEMM: out[16384][1024] = ocombb @ WoT^T + bo
    hipLaunchKernelGGL((gemm_bt_bf16<false>), dim3(DIMK / 64, MROWS / 128), dim3(256), 0, stream,
                       (const void*)ocombb, WoT, bo, out, MROWS, DIMK, CC);
}